// Round 4
// baseline (245.648 us; speedup 1.0000x reference)
//
#include <hip/hip_runtime.h>

#define NMID 19
#define LOG2E 1.4426950408889634f
#define LN2   0.6931471805599453f

typedef _Float16 h2 __attribute__((ext_vector_type(2)));

__device__ __forceinline__ h2 uph(unsigned int u) {
    return __builtin_bit_cast(h2, u);
}

// single v_cvt_pkrtz_f16_f32; bit_cast bridges __fp16x2 (builtin ret) -> h2
__device__ __forceinline__ h2 pk(float a, float b) {
    return __builtin_bit_cast(h2, __builtin_amdgcn_cvt_pkrtz(a, b));
}

__device__ __forceinline__ float exp2r(float x) {   // raw 2^x (v_exp_f32)
#if __has_builtin(__builtin_amdgcn_exp2f)
    return __builtin_amdgcn_exp2f(x);
#else
    return __expf(x * LN2);
#endif
}

__device__ __forceinline__ float log2r(float x) {   // raw log2 (v_log_f32)
#if __has_builtin(__builtin_amdgcn_logf)
    return __builtin_amdgcn_logf(x);
#else
    return __logf(x) * LOG2E;
#endif
}

// 2-wide f16 dot with f32 accumulate: v_dot2_f32_f16 (full-rate DL instr)
__device__ __forceinline__ float fdot2(h2 a, h2 b, float c) {
#if __has_builtin(__builtin_amdgcn_fdot2)
    return __builtin_amdgcn_fdot2(a, b, c, false);
#else
    return fmaf((float)a[0], (float)b[0], fmaf((float)a[1], (float)b[1], c));
#endif
}

// input: at = log2e * (pre-activation a). returns g = elu(a) + 1
//  a>0 : a+1  = at*ln2 + 1        (v_fma)
//  a<=0: e^a  = 2^at              (v_exp)
// 4 VALU ops total: exp, fma, cmp, cndmask
__device__ __forceinline__ float elu1(float at) {
    float e = exp2r(at);
    float p = fmaf(at, LN2, 1.0f);
    return (at > 0.0f) ? p : e;
}

// ---------------------------------------------------------------------------
// Workspace layout (u32 words):
//   [  0.. 13]  W~1 f32: LOG2E*W1[j][c]          (fc1 kept in f32 — exact input)
//   [ 14.. 20]  b~1 f32: LOG2E*b1[j]
//   [ 21..552]  wpm u32: l*28 + j*4 + kk -> half2(LOG2E*W[j][2kk], LOG2E*W[j][2kk+1]) (pad 0)
//   [553..685]  btm f32: LOG2E*(bm[l][j] - sum_k Wm[l][j][k])    (ELU "-1" folded)
//   [686..693]  wpo u32: c*4 + kk  -> half2 pairs of LOG2E*Wo[c][k]
//   [694..695]  bto f32: LOG2E*(bo[c] - sum_k Wo[c][k])
// ---------------------------------------------------------------------------
#define NWORDS 696

__device__ __forceinline__ unsigned int packh2(float a, float b) {
    _Float16 ha = (_Float16)a, hb = (_Float16)b;   // RTE
    unsigned short ua = __builtin_bit_cast(unsigned short, ha);
    unsigned short ub = __builtin_bit_cast(unsigned short, hb);
    return (unsigned int)ua | ((unsigned int)ub << 16);
}

__global__ void prep_kernel(const float* __restrict__ W1, const float* __restrict__ b1,
                            const float* __restrict__ Wm, const float* __restrict__ bm,
                            const float* __restrict__ Wo, const float* __restrict__ bo,
                            unsigned int* __restrict__ ws)
{
    for (int idx = threadIdx.x; idx < NWORDS; idx += blockDim.x) {
        unsigned int uv;
        if (idx < 14) {                                   // W~1 (f32)
            uv = __float_as_uint(LOG2E * W1[idx]);
        } else if (idx < 21) {                            // b~1
            uv = __float_as_uint(LOG2E * b1[idx - 14]);
        } else if (idx < 553) {                           // mid weight pairs (f16x2)
            int q = idx - 21, l = q / 28, r = q % 28, j = r / 4, kk = r % 4;
            const float* W = Wm + l * 49 + j * 7;
            float a = LOG2E * W[kk * 2 + 0];
            float b = (kk < 3) ? LOG2E * W[kk * 2 + 1] : 0.0f;
            uv = packh2(a, b);
        } else if (idx < 686) {                           // mid biases, -1 folded
            int q = idx - 553, l = q / 7, j = q % 7;
            const float* W = Wm + l * 49 + j * 7;
            float s = 0.0f;
#pragma unroll
            for (int k = 0; k < 7; ++k) s += W[k];
            uv = __float_as_uint(LOG2E * (bm[l * 7 + j] - s));
        } else if (idx < 694) {                           // fc21 weight pairs
            int q = idx - 686, c = q / 4, kk = q % 4;
            const float* W = Wo + c * 7;
            float a = LOG2E * W[kk * 2 + 0];
            float b = (kk < 3) ? LOG2E * W[kk * 2 + 1] : 0.0f;
            uv = packh2(a, b);
        } else {                                          // fc21 biases, -1 folded
            int c = idx - 694;
            const float* W = Wo + c * 7;
            float s = 0.0f;
#pragma unroll
            for (int k = 0; k < 7; ++k) s += W[k];
            uv = __float_as_uint(LOG2E * (bo[c] - s));
        }
        ws[idx] = uv;
    }
}

__global__ __launch_bounds__(256) void net_mlp_kernel(
    const float* __restrict__ x,
    const unsigned int* __restrict__ ws,
    float* __restrict__ out, int B)
{
    int i = blockIdx.x * blockDim.x + threadIdx.x;
    if (i >= B) return;

    const float* wsf = reinterpret_cast<const float*>(ws);
    const float2 xin = reinterpret_cast<const float2*>(x)[i];

    // fc1 in f32 (exact input, only 14 fma), producing log2e-scaled preacts
    float g[7];
#pragma unroll
    for (int j = 0; j < 7; ++j) {
        float at = fmaf(xin.x, wsf[j * 2 + 0],
                   fmaf(xin.y, wsf[j * 2 + 1], wsf[14 + j]));
        g[j] = elu1(at);
    }
    h2 gp0 = pk(g[0], g[1]);
    h2 gp1 = pk(g[2], g[3]);
    h2 gp2 = pk(g[4], g[5]);
    h2 gp3 = pk(g[6], 0.0f);

    // fc2..fc20: 28 dot2 + 28 ELU-ops + 4 packs per layer
#pragma unroll
    for (int l = 0; l < NMID; ++l) {
        const unsigned int* wp = ws + 21 + l * 28;   // uniform -> s_load
        const float* bt = wsf + 553 + l * 7;
        float ng[7];
#pragma unroll
        for (int j = 0; j < 7; ++j) {
            float a = fdot2(gp0, uph(wp[j * 4 + 0]), bt[j]);
            a       = fdot2(gp1, uph(wp[j * 4 + 1]), a);
            a       = fdot2(gp2, uph(wp[j * 4 + 2]), a);
            a       = fdot2(gp3, uph(wp[j * 4 + 3]), a);
            ng[j] = elu1(a);
        }
        gp0 = pk(ng[0], ng[1]);
        gp1 = pk(ng[2], ng[3]);
        gp2 = pk(ng[4], ng[5]);
        gp3 = pk(ng[6], 0.0f);
    }

    // fc21 + log_softmax (logits carried log2e-scaled; rescale by ln2 at the end)
    float l0 = fdot2(gp0, uph(ws[686]), wsf[694]);
    l0       = fdot2(gp1, uph(ws[687]), l0);
    l0       = fdot2(gp2, uph(ws[688]), l0);
    l0       = fdot2(gp3, uph(ws[689]), l0);
    float l1 = fdot2(gp0, uph(ws[690]), wsf[695]);
    l1       = fdot2(gp1, uph(ws[691]), l1);
    l1       = fdot2(gp2, uph(ws[692]), l1);
    l1       = fdot2(gp3, uph(ws[693]), l1);

    float m  = fmaxf(l0, l1);
    float d  = fminf(l0, l1) - m;                 // <= 0
    float zt = m + log2r(1.0f + exp2r(d));        // log2-sum-exp2, stable
    float2 o;
    o.x = (l0 - zt) * LN2;
    o.y = (l1 - zt) * LN2;
    reinterpret_cast<float2*>(out)[i] = o;
}

extern "C" void kernel_launch(void* const* d_in, const int* in_sizes, int n_in,
                              void* d_out, int out_size, void* d_ws, size_t ws_size,
                              hipStream_t stream) {
    const float* x  = (const float*)d_in[0];
    const float* W1 = (const float*)d_in[1];
    const float* b1 = (const float*)d_in[2];
    const float* Wm = (const float*)d_in[3];
    const float* bm = (const float*)d_in[4];
    const float* Wo = (const float*)d_in[5];
    const float* bo = (const float*)d_in[6];
    float* out = (float*)d_out;
    unsigned int* ws = (unsigned int*)d_ws;

    prep_kernel<<<1, 256, 0, stream>>>(W1, b1, Wm, bm, Wo, bo, ws);

    const int B = in_sizes[0] / 2;  // x is [B,2]
    const int block = 256;
    const int grid = (B + block - 1) / block;
    net_mlp_kernel<<<grid, block, 0, stream>>>(x, ws, out, B);
}

// Round 7
// 224.171 us; speedup vs baseline: 1.0958x; 1.0958x over previous
//
#include <hip/hip_runtime.h>
#include <hip/hip_fp16.h>

#define NMID 19
#define LOG2E 1.4426950408889634f
#define LN2   0.6931471805599453f

// ---------------------------------------------------------------------------
// Workspace layout (u32 words):
//   [   0..  13] W~1 f32: LOG2E*W1[j][c]           (fc1 in f32 — exact input)
//   [  14..  20] b~1 f32: LOG2E*b1[j]
//   [  21.. 951] Wm rep-h2: l*49+j*7+k -> f16(LOG2E*Wm[l][j][k]) replicated both halves
//   [ 952..1084] bm' rep-h2: l*7+j -> f16(LOG2E*(bm[l][j]-sum_k W)) replicated ("-1" fold)
//   [1085..1098] Wo~ f32: c*7+k -> LOG2E*Wo[c][k]
//   [1099..1100] bo' f32: LOG2E*(bo[c]-sum_k Wo[c][k])
// ---------------------------------------------------------------------------
#define W1_OFF 0
#define B1_OFF 14
#define WM_OFF 21
#define BM_OFF 952
#define WO_OFF 1085
#define BO_OFF 1099
#define NWORDS 1101

typedef _Float16 v2h __attribute__((ext_vector_type(2)));

__device__ __forceinline__ float exp2r(float x) {
#if __has_builtin(__builtin_amdgcn_exp2f)
    return __builtin_amdgcn_exp2f(x);
#else
    return __expf(x * LN2);
#endif
}
__device__ __forceinline__ float log2r(float x) {
#if __has_builtin(__builtin_amdgcn_logf)
    return __builtin_amdgcn_logf(x);
#else
    return __logf(x) * LOG2E;
#endif
}

// packed f16 min/max: ROCm 7.2 fp16 header has no __hmin2/__hmax2 —
// use clang elementwise builtins on native fp16 vectors (-> v_pk_min/max_f16)
__device__ __forceinline__ __half2 pmin2(__half2 a, __half2 b) {
    v2h av = __builtin_bit_cast(v2h, a), bv = __builtin_bit_cast(v2h, b);
    return __builtin_bit_cast(__half2, __builtin_elementwise_min(av, bv));
}
__device__ __forceinline__ __half2 pmax2(__half2 a, __half2 b) {
    v2h av = __builtin_bit_cast(v2h, a), bv = __builtin_bit_cast(v2h, b);
    return __builtin_bit_cast(__half2, __builtin_elementwise_max(av, bv));
}

// f32 -> f16 (RTE), replicated into both halves of a u32
__device__ __forceinline__ unsigned int reph(float v) {
    _Float16 h = (_Float16)v;
    unsigned short u = __builtin_bit_cast(unsigned short, h);
    return (unsigned int)u * 0x00010001u;
}

__global__ void prep_kernel(const float* __restrict__ W1, const float* __restrict__ b1,
                            const float* __restrict__ Wm, const float* __restrict__ bm,
                            const float* __restrict__ Wo, const float* __restrict__ bo,
                            unsigned int* __restrict__ ws)
{
    for (int idx = threadIdx.x; idx < NWORDS; idx += blockDim.x) {
        unsigned int uv;
        if (idx < B1_OFF) {                                // W~1 (f32)
            uv = __float_as_uint(LOG2E * W1[idx]);
        } else if (idx < WM_OFF) {                         // b~1 (f32)
            uv = __float_as_uint(LOG2E * b1[idx - B1_OFF]);
        } else if (idx < BM_OFF) {                         // mid weights, replicated f16
            int q = idx - WM_OFF;                          // l*49 + j*7 + k
            uv = reph(LOG2E * Wm[q]);
        } else if (idx < WO_OFF) {                         // mid biases, -1 folded, replicated
            int q = idx - BM_OFF, l = q / 7, j = q % 7;
            const float* W = Wm + l * 49 + j * 7;
            float s = 0.0f;
#pragma unroll
            for (int k = 0; k < 7; ++k) s += W[k];
            uv = reph(LOG2E * (bm[l * 7 + j] - s));
        } else if (idx < BO_OFF) {                         // fc21 weights (f32)
            int q = idx - WO_OFF;                          // c*7 + k
            uv = __float_as_uint(LOG2E * Wo[q]);
        } else {                                           // fc21 biases, -1 folded (f32)
            int c = idx - BO_OFF;
            const float* W = Wo + c * 7;
            float s = 0.0f;
#pragma unroll
            for (int k = 0; k < 7; ++k) s += W[k];
            uv = __float_as_uint(LOG2E * (bo[c] - s));
        }
        ws[idx] = uv;
    }
}

// packed ELU+1 in log2e domain, branchless, no cross-half select:
//   E = 2^at ; P = at*ln2 + 1 ; since 2^x >= x*ln2+1 for all x:
//   at<=0: min(E,1)=E, max(P,1)=1 -> E      (= e^a)
//   at> 0: min(E,1)=1, max(P,1)=P -> P      (= a+1)
//   (multiply by exactly 1.0 is exact in fp16)
__device__ __forceinline__ __half2 pelu(__half2 at, __half2 ln22, __half2 one2) {
    __half2 E = h2exp2(at);
    __half2 P = __hfma2(at, ln22, one2);
    return __hmul2(pmin2(E, one2), pmax2(P, one2));
}

__global__ __launch_bounds__(256) void net_mlp_kernel(
    const float* __restrict__ x,
    const unsigned int* __restrict__ ws,
    float* __restrict__ out, int B)
{
    int i = blockIdx.x * blockDim.x + threadIdx.x;   // handles rows 2i, 2i+1
    if (2 * i >= B) return;

    const float* wsf = reinterpret_cast<const float*>(ws);
    const __half2* wsh = reinterpret_cast<const __half2*>(ws);

    const float4 xx = reinterpret_cast<const float4*>(x)[i];  // rowA=(x,y) rowB=(z,w)

    const __half2 one2 = __float2half2_rn(1.0f);
    const __half2 ln22 = __float2half2_rn(LN2);

    // fc1 in f32 (exact input), pack preacts rowA/rowB into halves, packed ELU
    __half2 g[7];
#pragma unroll
    for (int j = 0; j < 7; ++j) {
        float w0 = wsf[W1_OFF + 2 * j], w1 = wsf[W1_OFF + 2 * j + 1], bb = wsf[B1_OFF + j];
        float aA = fmaf(xx.x, w0, fmaf(xx.y, w1, bb));
        float aB = fmaf(xx.z, w0, fmaf(xx.w, w1, bb));
        g[j] = pelu(__floats2half2_rn(aA, aB), ln22, one2);
    }

    // fc2..fc20: 49 v_pk_fma_f16 (2 rows/lane) + 7 packed ELU per layer
#pragma unroll
    for (int l = 0; l < NMID; ++l) {
        const __half2* wp = wsh + WM_OFF + l * 49;   // wave-uniform -> s_load
        const __half2* bp = wsh + BM_OFF + l * 7;
        __half2 ng[7];
#pragma unroll
        for (int j = 0; j < 7; ++j) {
            __half2 acc = bp[j];
#pragma unroll
            for (int k = 0; k < 7; ++k)
                acc = __hfma2(g[k], wp[j * 7 + k], acc);
            ng[j] = pelu(acc, ln22, one2);
        }
#pragma unroll
        for (int j = 0; j < 7; ++j) g[j] = ng[j];
    }

    // fc21 + log_softmax in f32 (logits precision matters; carried log2e-scaled)
    float l0A = wsf[BO_OFF + 0], l1A = wsf[BO_OFF + 1];
    float l0B = l0A, l1B = l1A;
#pragma unroll
    for (int k = 0; k < 7; ++k) {
        float gA = __low2float(g[k]);
        float gB = __high2float(g[k]);
        float w0 = wsf[WO_OFF + k], w1 = wsf[WO_OFF + 7 + k];
        l0A = fmaf(gA, w0, l0A);
        l1A = fmaf(gA, w1, l1A);
        l0B = fmaf(gB, w0, l0B);
        l1B = fmaf(gB, w1, l1B);
    }

    float4 o;
    {
        float m = fmaxf(l0A, l1A), d = fminf(l0A, l1A) - m;
        float zt = m + log2r(1.0f + exp2r(d));
        o.x = (l0A - zt) * LN2;
        o.y = (l1A - zt) * LN2;
    }
    {
        float m = fmaxf(l0B, l1B), d = fminf(l0B, l1B) - m;
        float zt = m + log2r(1.0f + exp2r(d));
        o.z = (l0B - zt) * LN2;
        o.w = (l1B - zt) * LN2;
    }
    reinterpret_cast<float4*>(out)[i] = o;   // rows 2i,2i+1 contiguous, coalesced 16B
}

extern "C" void kernel_launch(void* const* d_in, const int* in_sizes, int n_in,
                              void* d_out, int out_size, void* d_ws, size_t ws_size,
                              hipStream_t stream) {
    const float* x  = (const float*)d_in[0];
    const float* W1 = (const float*)d_in[1];
    const float* b1 = (const float*)d_in[2];
    const float* Wm = (const float*)d_in[3];
    const float* bm = (const float*)d_in[4];
    const float* Wo = (const float*)d_in[5];
    const float* bo = (const float*)d_in[6];
    float* out = (float*)d_out;
    unsigned int* ws = (unsigned int*)d_ws;

    prep_kernel<<<1, 256, 0, stream>>>(W1, b1, Wm, bm, Wo, bo, ws);

    const int B = in_sizes[0] / 2;          // x is [B,2]
    const int pairs = (B + 1) / 2;          // 2 rows per thread
    const int block = 256;
    const int grid = (pairs + block - 1) / block;
    net_mlp_kernel<<<grid, block, 0, stream>>>(x, ws, out, B);
}